// Round 12
// baseline (338.743 us; speedup 1.0000x reference)
//
#include <hip/hip_runtime.h>
#include <hip/hip_bf16.h>

// Problem constants (fixed by setup_inputs)
#define BQ      2
#define QLEN    16384            // 128*128
#define CDIM    256
#define HEADS   8
#define LEV     3
#define PTS     4
#define DHEAD   32
#define NVTOT   13125            // 100*100 + 50*50 + 25*25
#define FDIM    1024
#define NTOK    (BQ*QLEN)        // 32768
#define MROWS_V (BQ*NVTOT)       // 26250
#define NPROJ   288              // 192 offsets + 96 attn logits, fused
#define VP_GX   206              // (MROWS_V+127)/128

typedef __attribute__((ext_vector_type(8))) short short8;     // 8 bf16 = 4 VGPRs
typedef __attribute__((ext_vector_type(4))) float floatx4;    // MFMA acc
typedef unsigned long long u64;

typedef const __attribute__((address_space(1))) unsigned int gu32;
typedef __attribute__((address_space(3))) unsigned int lu32;

__device__ __forceinline__ int imin(int a, int b){ return a<b?a:b; }
__device__ __forceinline__ int imax(int a, int b){ return a>b?a:b; }

__device__ __forceinline__ float bf2f(unsigned short u){ return __uint_as_float((unsigned)u << 16); }
__device__ __forceinline__ unsigned short f2bf(float f)
{
    __hip_bfloat16 h = __float2bfloat16(f);
    return *(unsigned short*)&h;
}
__device__ __forceinline__ u64 pack4(float4 v)
{
    return (u64)f2bf(v.x) | ((u64)f2bf(v.y) << 16)
         | ((u64)f2bf(v.z) << 32) | ((u64)f2bf(v.w) << 48);
}
__device__ __forceinline__ float4 unpack4(u64 c)
{
    float4 v;
    v.x = bf2f((unsigned short)(c));
    v.y = bf2f((unsigned short)(c >> 16));
    v.z = bf2f((unsigned short)(c >> 32));
    v.w = bf2f((unsigned short)(c >> 48));
    return v;
}

// tanh-gelu via exp + hardware rcp (no div sequence); err ~3e-4, saturation-safe
__device__ __forceinline__ float gelu_f(float x)
{
    float u2 = x * x;
    float a  = x * fmaf(0.0713548163f, u2, 1.5957691216f);  // 2u
    float e  = __expf(a);
    float r  = __builtin_amdgcn_rcpf(e + 1.0f);
    return fmaf(-x, r, x);   // x * e/(e+1)
}

// LayerNorm core: one wave per token (4 ch per lane), bf16 out
__device__ __forceinline__ void ln_core(float4 v, const float* __restrict__ pos, int tok,
                                        const float* __restrict__ g, const float* __restrict__ b,
                                        int lane, __hip_bfloat16* __restrict__ out)
{
    float s = v.x + v.y + v.z + v.w;
    #pragma unroll
    for (int o = 32; o > 0; o >>= 1) s += __shfl_down(s, o);
    s = __shfl(s, 0);
    float mean = s * (1.0f / 256.0f);
    float4 c; c.x = v.x - mean; c.y = v.y - mean; c.z = v.z - mean; c.w = v.w - mean;
    float q2 = c.x*c.x + c.y*c.y + c.z*c.z + c.w*c.w;
    #pragma unroll
    for (int o = 32; o > 0; o >>= 1) q2 += __shfl_down(q2, o);
    q2 = __shfl(q2, 0);
    float rstd = rsqrtf(q2 * (1.0f / 256.0f) + 1e-5f);
    float4 gg = ((const float4*)g)[lane];
    float4 bb = ((const float4*)b)[lane];
    float4 o4;
    o4.x = c.x * rstd * gg.x + bb.x;
    o4.y = c.y * rstd * gg.y + bb.y;
    o4.z = c.z * rstd * gg.z + bb.z;
    o4.w = c.w * rstd * gg.w + bb.w;
    if (pos) {
        float4 p = ((const float4*)(pos + (size_t)tok * CDIM))[lane];
        o4.x += p.x; o4.y += p.y; o4.z += p.z; o4.w += p.w;
    }
    *(u64*)(out + (size_t)tok * CDIM + lane * 4) = pack4(o4);
}

// ---------------------------------------------------------------- prep: weight transpose+cvt + value cvt + LN1, one launch
// W1/W2 are written in MFMA-fragment order for ffn_k: chunk index
// fc*4096 + wn*1024 + r*64 + lane (16B per lane) so every ffn_k weight load
// is a fully coalesced 64-lane x 16B request.
#define WT_BLOCKS  2946
#define CVT_BLOCKS 6563          // ceil(26250*256/4 / 256)
#define LN_BLOCKS  8192          // NTOK/4

__global__ __launch_bounds__(256)
void prep_k(const float* __restrict__ Wv,  const float* __restrict__ Woff,
            const float* __restrict__ Wat, const float* __restrict__ Wout,
            const float* __restrict__ W1,  const float* __restrict__ W2,
            const float* __restrict__ boff, const float* __restrict__ bat,
            const float* __restrict__ value, const float* __restrict__ query,
            const float* __restrict__ qpos,  const float* __restrict__ ln1g,
            const float* __restrict__ ln1b,
            __hip_bfloat16* __restrict__ o_v,  __hip_bfloat16* __restrict__ o_c,
            __hip_bfloat16* __restrict__ o_out,
            __hip_bfloat16* __restrict__ o_1,  __hip_bfloat16* __restrict__ o_2,
            float* __restrict__ o_bc,
            __hip_bfloat16* __restrict__ vbf,  __hip_bfloat16* __restrict__ qbf)
{
    int bx = blockIdx.x;
    if (bx < WT_BLOCKS) {
        int gid = bx * 256 + threadIdx.x;
        if (gid < 65536) {                      // Wv  -> [256][256]
            int idx = gid, n = idx >> 8, k = idx & 255;
            o_v[idx] = __float2bfloat16(Wv[(size_t)k * 256 + n]);
        } else if (gid < 163840) {              // combined proj -> [384][256]
            int idx = gid - 65536, n = idx >> 8, k = idx & 255;
            float v = 0.0f;
            if (n < 192)       v = Woff[(size_t)k * 192 + n];
            else if (n < 288)  v = Wat[(size_t)k * 96 + (n - 192)];
            o_c[idx] = __float2bfloat16(v);
        } else if (gid < 229376) {              // Wout -> [256][256]
            int idx = gid - 163840, n = idx >> 8, k = idx & 255;
            o_out[idx] = __float2bfloat16(Wout[(size_t)k * 256 + n]);
        } else if (gid < 491520) {              // W1 -> ffn frag-packed [32768 chunks][8]
            int idx  = gid - 229376;
            int e    = idx & 7;
            int c    = idx >> 3;
            int lane = c & 63, lm = lane & 15, lk = lane >> 4;
            int r    = (c >> 6) & 15;
            int wn   = (c >> 10) & 3;
            int fc   = c >> 12;
            int i    = r & 1, ks = (r >> 1) & 1, kt = r >> 2;
            int row  = fc * 128 + wn * 32 + i * 16 + lm;   // F index 0..1023
            int col  = kt * 64 + ks * 32 + lk * 8 + e;     // K index 0..255
            o_1[idx] = __float2bfloat16(W1[(size_t)col * 1024 + row]);
        } else if (gid < 753664) {              // W2 -> ffn frag-packed [32768 chunks][8]
            int idx  = gid - 491520;
            int e    = idx & 7;
            int c    = idx >> 3;
            int lane = c & 63, lm = lane & 15, lk = lane >> 4;
            int r    = (c >> 6) & 15;
            int wn   = (c >> 10) & 3;
            int fc   = c >> 12;
            int i2   = r & 3, ks2 = r >> 2;
            int row  = wn * 64 + i2 * 16 + lm;             // C index 0..255
            int col  = fc * 128 + ks2 * 32 + lk * 8 + e;   // F index 0..1023
            o_2[idx] = __float2bfloat16(W2[(size_t)col * 256 + row]);
        } else if (gid < 753952) {              // combined bias [288]
            int idx = gid - 753664;
            o_bc[idx] = (idx < 192) ? boff[idx] : bat[idx - 192];
        }
    } else if (bx < WT_BLOCKS + CVT_BLOCKS) {
        int i = (bx - WT_BLOCKS) * 256 + threadIdx.x;
        if (i < MROWS_V * CDIM / 4) {
            float4 v = ((const float4*)value)[i];
            *(u64*)(vbf + (size_t)i * 4) = pack4(v);
        }
    } else {
        int tok  = (bx - WT_BLOCKS - CVT_BLOCKS) * 4 + (threadIdx.x >> 6);
        int lane = threadIdx.x & 63;
        float4 v = ((const float4*)(query + (size_t)tok * CDIM))[lane];
        ln_core(v, qpos, tok, ln1g, ln1b, lane, qbf);
    }
}

// ---------------------------------------------------------------- LN2: bf16 in, bf16 out
__global__ __launch_bounds__(256)
void ln2_k(const __hip_bfloat16* __restrict__ x, const float* __restrict__ g,
           const float* __restrict__ b, __hip_bfloat16* __restrict__ out)
{
    int tok  = blockIdx.x * 4 + (threadIdx.x >> 6);
    int lane = threadIdx.x & 63;
    float4 v = unpack4(((const u64*)(x + (size_t)tok * CDIM))[lane]);
    ln_core(v, nullptr, tok, g, b, lane, out);
}

// ---------------------------------------------------------------- bf16 MFMA GEMM body (transposed-acc + single-pass bf16-staged epilogue)
// modes: 0 = plain bf16 out; 1 = gelu bf16 out; 2 = +fp32 res -> bf16 out; 3 = +bf16 res -> fp32 out
enum { EP_PLAIN_BF16 = 0, EP_GELU_BF16 = 1, EP_RES_F2BF = 2, EP_RES_BF2F = 3 };

__device__ __forceinline__
void mm_body(float4* smem4,
             const __hip_bfloat16* __restrict__ A, const __hip_bfloat16* __restrict__ Bt,
             const float* __restrict__ bias, const void* __restrict__ res,
             void* __restrict__ Cout, int M, int N, int K, int mode)
{
    __hip_bfloat16* Ws = (__hip_bfloat16*)smem4;          // 16 KB weight tile
    __hip_bfloat16* Ts = (__hip_bfloat16*)smem4 + 128*64; // 16 KB token tile
    u64* st = (u64*)smem4;                                // staging: 128 tok x 32 chunks x 8B
    int t = threadIdx.x;
    int lane = t & 63;
    int wave = t >> 6;
    int wm = wave >> 1, wn = wave & 1;
    int lm = lane & 15, lk = lane >> 4;
    int m0 = blockIdx.x * 128;     // token base
    int n0 = blockIdx.y * 128;     // channel base

    floatx4 acc[4][4];             // [i: channel subtile][j: token subtile]
    #pragma unroll
    for (int i = 0; i < 4; i++)
        #pragma unroll
        for (int j = 0; j < 4; j++) acc[i][j] = (floatx4)0.0f;

    for (int kt = 0; kt < K; kt += 64) {
        #pragma unroll
        for (int i = 0; i < 4; i++) {
            int cc  = i * 256 + t;          // LDS chunk 0..1023 (16 B each)
            int row = cc >> 3;              // 0..127
            int c   = cc & 7;
            int kc  = c ^ (row & 7);        // XOR swizzle
            int ra  = m0 + row; if (ra >= M) ra = M - 1;   // token row clamp
            const __hip_bfloat16* gw = Bt + (size_t)(n0 + row) * K + kt + kc * 8;
            const __hip_bfloat16* gt = A  + (size_t)ra * K + kt + kc * 8;
            __builtin_amdgcn_global_load_lds((gu32*)gw, (lu32*)(Ws + cc * 8), 16, 0, 0);
            __builtin_amdgcn_global_load_lds((gu32*)gt, (lu32*)(Ts + cc * 8), 16, 0, 0);
        }
        __syncthreads();
        #pragma unroll
        for (int ks = 0; ks < 2; ks++) {
            short8 wf[4], tf[4];
            #pragma unroll
            for (int i = 0; i < 4; i++) {
                int rw = wn * 64 + i * 16 + lm;            // channel row
                int cw = (ks * 4 + lk) ^ (rw & 7);
                wf[i] = *(const short8*)(Ws + (rw * 8 + cw) * 8);
                int rt = wm * 64 + i * 16 + lm;            // token row
                int ct = (ks * 4 + lk) ^ (rt & 7);
                tf[i] = *(const short8*)(Ts + (rt * 8 + ct) * 8);
            }
            #pragma unroll
            for (int i = 0; i < 4; i++)
                #pragma unroll
                for (int j = 0; j < 4; j++)
                    acc[i][j] = __builtin_amdgcn_mfma_f32_16x16x32_bf16(wf[i], tf[j], acc[i][j], 0, 0, 0);
        }
        __syncthreads();
    }

    // ---- write side: all waves stage bias-added bf16 frags ----
    #pragma unroll
    for (int i = 0; i < 4; i++) {
        int chan = n0 + wn * 64 + i * 16 + lk * 4;
        float4 b4 = make_float4(0.f, 0.f, 0.f, 0.f);
        if (chan < N) b4 = *(const float4*)(bias + chan);
        int c4 = wn * 16 + i * 4 + lk;          // chan chunk 0..31
        #pragma unroll
        for (int j = 0; j < 4; j++) {
            int tl = wm * 64 + j * 16 + lm;     // token-local 0..127
            float4 v;
            v.x = acc[i][j][0] + b4.x;
            v.y = acc[i][j][1] + b4.y;
            v.z = acc[i][j][2] + b4.z;
            v.w = acc[i][j][3] + b4.w;
            st[tl * 32 + (c4 ^ (tl & 31))] = pack4(v);
        }
    }
    __syncthreads();

    // ---- read side: coalesced row-contiguous stores ----
    int rel = (t & 31) * 4;
    int c4r = t & 31;
    #pragma unroll
    for (int it = 0; it < 16; it++) {
        int tl   = it * 8 + (t >> 5);
        int tok  = m0 + tl;
        int chan = n0 + rel;
        if (tok >= M || chan >= N) continue;
        u64 chunk = st[tl * 32 + (c4r ^ (tl & 31))];
        if (mode == EP_PLAIN_BF16) {
            *(u64*)((__hip_bfloat16*)Cout + (size_t)tok * N + chan) = chunk;
        } else if (mode == EP_GELU_BF16) {
            float4 v = unpack4(chunk);
            v.x = gelu_f(v.x); v.y = gelu_f(v.y); v.z = gelu_f(v.z); v.w = gelu_f(v.w);
            *(u64*)((__hip_bfloat16*)Cout + (size_t)tok * N + chan) = pack4(v);
        } else if (mode == EP_RES_F2BF) {
            float4 v = unpack4(chunk);
            float4 rr = *(const float4*)((const float*)res + (size_t)tok * N + chan);
            v.x += rr.x; v.y += rr.y; v.z += rr.z; v.w += rr.w;
            *(u64*)((__hip_bfloat16*)Cout + (size_t)tok * N + chan) = pack4(v);
        } else { // EP_RES_BF2F
            float4 v = unpack4(chunk);
            float4 rr = unpack4(*(const u64*)((const __hip_bfloat16*)res + (size_t)tok * N + chan));
            v.x += rr.x; v.y += rr.y; v.z += rr.z; v.w += rr.w;
            *(float4*)((float*)Cout + (size_t)tok * N + chan) = v;
        }
    }
}

__global__ __launch_bounds__(256)
void mm_k(const __hip_bfloat16* __restrict__ A, const __hip_bfloat16* __restrict__ Bt,
          const float* __restrict__ bias, const void* __restrict__ res,
          void* __restrict__ Cout, int M, int N, int K, int mode)
{
    __shared__ float4 smem4[2048];                    // 32 KB
    mm_body(smem4, A, Bt, bias, res, Cout, M, N, K, mode);
}

// Merged launch for the two independent GEMMs after prep (v-proj + fused proj):
// z=0 -> vproj (206x2 blocks), z=1 -> proj (256x3 blocks). Combined grid fills
// the tails (vproj alone leaves 50 CUs idle and serializes behind a launch gap).
__global__ __launch_bounds__(256)
void mmj_k(const __hip_bfloat16* __restrict__ vbf, const __hip_bfloat16* __restrict__ Wvt,
           const float* __restrict__ bv, __hip_bfloat16* __restrict__ vbuf,
           const __hip_bfloat16* __restrict__ qbf, const __hip_bfloat16* __restrict__ Wct,
           const float* __restrict__ bcomb, __hip_bfloat16* __restrict__ cbuf)
{
    __shared__ float4 smem4[2048];                    // 32 KB
    if (blockIdx.z == 0) {
        if (blockIdx.x >= VP_GX || blockIdx.y >= 2) return;
        mm_body(smem4, vbf, Wvt, bv, nullptr, vbuf, MROWS_V, 256, 256, EP_PLAIN_BF16);
    } else {
        mm_body(smem4, qbf, Wct, bcomb, nullptr, cbuf, NTOK, NPROJ, 256, EP_PLAIN_BF16);
    }
}

// ---------------------------------------------------------------- fused FFN: out = x + gelu(h@W1+b1)@W2 + b2
// ROUND-11 POST-MORTEM: LN2-in-LDS fusion fired its falsifier (ffn_k 61->67.2us,
// +65K bank-conflict cycles; the per-wave 16-iter serial LN loop with two
// cross-lane reduces each costs more than the ~6-7us standalone ln2_k it
// replaced). Reverted to the round-8 ffn_k, measured 61.0us three times:
// 128-token tile, 512 threads, 2-barrier/fc, frag-packed coalesced weight
// loads, in-place w1c prefetch. Backend gives 512-thread blocks 128 VGPRs
// (observed rounds 4-8 regardless of launch_bounds hint); mild ~5MB spill.
__global__ __launch_bounds__(512, 1)
void ffn_k(const __hip_bfloat16* __restrict__ h,    // [NTOK][256] bf16 (LN2 out)
           const __hip_bfloat16* __restrict__ W1p,  // frag-packed [32768][8] bf16
           const float* __restrict__ b1,            // [1024]
           const __hip_bfloat16* __restrict__ W2p,  // frag-packed [32768][8] bf16
           const float* __restrict__ b2,            // [256]
           const __hip_bfloat16* __restrict__ xres, // [NTOK][256] bf16 residual
           float* __restrict__ out)                 // [NTOK][256] fp32
{
    extern __shared__ char smem_dyn[];
    __hip_bfloat16* As = (__hip_bfloat16*)smem_dyn;           // 64KB: 4 kt-subtiles, mm_k layout

    int t    = threadIdx.x;
    int lane = t & 63;
    int wave = t >> 6;          // 0..7
    int wm   = wave >> 2;       // token half (64)
    int wn   = wave & 3;        // F quarter (32) in GEMM1 / C quarter (64) in GEMM2
    int lm   = lane & 15, lk = lane >> 4;
    int m0   = blockIdx.x * 128;

    const short8* W1v = (const short8*)W1p;
    const short8* W2v = (const short8*)W2p;
    int wb = wn * 1024 + lane;          // per-wave chunk base (lane-resolved)

    // ---- stage h-tile once: [4 kt][128 row][8 chunks of 16B], XOR swizzled ----
    #pragma unroll
    for (int i = 0; i < 8; i++) {
        int cc  = i * 512 + t;          // 0..4095 chunks
        int kt  = cc >> 10;
        int rem = cc & 1023;
        int row = rem >> 3;
        int c   = rem & 7;
        int kc  = c ^ (row & 7);
        const __hip_bfloat16* src = h + (size_t)(m0 + row) * 256 + kt * 64 + kc * 8;
        __builtin_amdgcn_global_load_lds((gu32*)src, (lu32*)(As + cc * 8), 16, 0, 0);
    }

    floatx4 acc2[4][4];                 // [i2: C subtile][j: tok subtile]
    #pragma unroll
    for (int i = 0; i < 4; i++)
        #pragma unroll
        for (int j = 0; j < 4; j++) acc2[i][j] = (floatx4)0.0f;

    // ---- preload W1 frags for fc=0 (coalesced; overlaps the staging drain) ----
    short8 w1c[16];                     // [kt*4 + ks*2 + i]
    #pragma unroll
    for (int r = 0; r < 16; r++) w1c[r] = W1v[wb + r * 64];

    __syncthreads();                    // As ready (vmcnt drained by barrier)

    #pragma unroll 1
    for (int fc = 0; fc < 8; fc++) {
        int f0 = fc * 128;
        __hip_bfloat16* gs = (__hip_bfloat16*)(smem_dyn + 65536 + (fc & 1) * 32768);

        // ---- GEMM1: acc1[f][tok] over K=256, W1 frags already in registers ----
        floatx4 acc1[2][4];
        #pragma unroll
        for (int i = 0; i < 2; i++)
            #pragma unroll
            for (int j = 0; j < 4; j++) acc1[i][j] = (floatx4)0.0f;

        #pragma unroll
        for (int kt = 0; kt < 4; kt++) {
            #pragma unroll
            for (int ks = 0; ks < 2; ks++) {
                short8 tf[4];
                #pragma unroll
                for (int j = 0; j < 4; j++) {
                    int rt = wm * 64 + j * 16 + lm;
                    int ct = (ks * 4 + lk) ^ (rt & 7);
                    tf[j] = *(const short8*)(As + (kt * 1024 + rt * 8 + ct) * 8);
                }
                #pragma unroll
                for (int i = 0; i < 2; i++)
                    #pragma unroll
                    for (int j = 0; j < 4; j++)
                        acc1[i][j] = __builtin_amdgcn_mfma_f32_16x16x32_bf16(
                            w1c[kt * 4 + ks * 2 + i], tf[j], acc1[i][j], 0, 0, 0);
            }
        }

        // ---- epilogue1: bias + gelu -> bf16 -> gs (XOR-swizzled [tok][16 chunks]) ----
        #pragma unroll
        for (int i = 0; i < 2; i++) {
            float4 bb = *(const float4*)(b1 + f0 + wn * 32 + i * 16 + lk * 4);
            int c = wn * 4 + i * 2 + (lk >> 1);      // 16B chunk index 0..15
            #pragma unroll
            for (int j = 0; j < 4; j++) {
                int tok = wm * 64 + j * 16 + lm;
                float4 v;
                v.x = gelu_f(acc1[i][j][0] + bb.x);
                v.y = gelu_f(acc1[i][j][1] + bb.y);
                v.z = gelu_f(acc1[i][j][2] + bb.z);
                v.w = gelu_f(acc1[i][j][3] + bb.w);
                int sc = c ^ (tok & 7);
                *(u64*)((char*)gs + tok * 256 + sc * 16 + (lk & 1) * 8) = pack4(v);
            }
        }

        // ---- W2 frags + next-fc W1 (in place into w1c; dead after GEMM1),
        //      both issued before the barrier so latency hides under it ----
        short8 w2f[16];                 // [ks2*4 + i2]
        #pragma unroll
        for (int r = 0; r < 16; r++) w2f[r] = W2v[fc * 4096 + wb + r * 64];

        int fcn = (fc < 7) ? fc + 1 : 7;
        #pragma unroll
        for (int r = 0; r < 16; r++) w1c[r] = W1v[fcn * 4096 + wb + r * 64];

        __syncthreads();                // gs writes visible to all waves

        // ---- GEMM2: acc2 += W2 x g over K=128 ----
        #pragma unroll
        for (int ks2 = 0; ks2 < 4; ks2++) {
            short8 tf2[4];
            #pragma unroll
            for (int j = 0; j < 4; j++) {
                int tok = wm * 64 + j * 16 + lm;
                int sc = (ks2 * 4 + lk) ^ (tok & 7);
                tf2[j] = *(const short8*)((char*)gs + tok * 256 + sc * 16);
            }
            #pragma unroll
            for (int i2 = 0; i2 < 4; i2++)
                #pragma unroll
                for (int j = 0; j < 4; j++)
                    acc2[i2][j] = __builtin_amdgcn_mfma_f32_16x16x32_bf16(
                        w2f[ks2 * 4 + i2], tf2[j], acc2[i2][j], 0, 0, 0);
        }
        // no trailing barrier: next fc writes the other gs buffer; the barrier
        // above (fc+1) orders GEMM2(fc) reads before epilogue1(fc+2) reuse.
    }

    // ---- final epilogue: + b2 + residual(bf16) -> fp32 out, 64B/tok segments ----
    #pragma unroll
    for (int i2 = 0; i2 < 4; i2++) {
        int c0 = wn * 64 + i2 * 16 + lk * 4;
        float4 bb = *(const float4*)(b2 + c0);
        #pragma unroll
        for (int j = 0; j < 4; j++) {
            int tok = m0 + wm * 64 + j * 16 + lm;
            float4 r = unpack4(*(const u64*)(xres + (size_t)tok * 256 + c0));
            float4 v;
            v.x = acc2[i2][j][0] + bb.x + r.x;
            v.y = acc2[i2][j][1] + bb.y + r.y;
            v.z = acc2[i2][j][2] + bb.z + r.z;
            v.w = acc2[i2][j][3] + bb.w + r.w;
            *(float4*)(out + (size_t)tok * 256 + c0) = v;
        }
    }
}

// ---------------------------------------------------------------- deformable sampling
// vbuf layout [b*NVTOT+pix][h*d]: wave-uniform base + 32-bit byte offsets (meta
// stores pix<<9); lane = (h, c8), per-lane byte bias = lane*8.
// Gather loop is depth-2 software-pipelined: point p+2's 4 gathers are issued
// while point p is consumed, so the compiler emits counted vmcnt (8 loads in
// flight) instead of draining vmcnt(0) every point. launch_bounds(256,6) caps
// VGPRs at ~85 so the unroll can't hoist all 48 loads and kill occupancy.
__global__ __launch_bounds__(256, 6)
void sample_k(const __hip_bfloat16* __restrict__ v, const __hip_bfloat16* __restrict__ cbuf,
              const float* __restrict__ ref, __hip_bfloat16* __restrict__ out)
{
    __shared__ int4   metaIdx[4 * 104];   // stride 13 slots -> conflict-free
    __shared__ float4 metaW[4 * 104];

    int wid  = threadIdx.x >> 6;
    int lane = threadIdx.x & 63;
    int t    = blockIdx.x * 4 + wid;
    int b    = t >> 14;
    float rx = ref[(size_t)t * 2 + 0];
    float ry = ref[(size_t)t * 2 + 1];
    const __hip_bfloat16* crow = cbuf + (size_t)t * NPROJ;

    #pragma unroll
    for (int rnd = 0; rnd < 2; rnd++) {
        int slot = rnd * 64 + lane;
        int h = slot >> 4, p = slot & 15;
        int pc = imin(p, 11);
        unsigned upk = *(const unsigned*)(crow + h * 24 + pc * 2);
        float ox = bf2f((unsigned short)upk);
        float oy = bf2f((unsigned short)(upk >> 16));
        float logit = bf2f(*(const unsigned short*)(crow + 192 + h * 12 + pc));
        float mx = logit;
        #pragma unroll
        for (int o = 8; o > 0; o >>= 1) mx = fmaxf(mx, __shfl_xor(mx, o, 16));
        float e = (p < 12) ? __expf(logit - mx) : 0.0f;
        float ssum = e;
        #pragma unroll
        for (int o = 8; o > 0; o >>= 1) ssum += __shfl_xor(ssum, o, 16);
        float aw = e * __builtin_amdgcn_rcpf(ssum);

        if (p < 12) {
            int l = p >> 2;
            float fS = (l == 0) ? 100.0f : ((l == 1) ? 50.0f : 25.0f);
            int   Wl = (l == 0) ? 100 : ((l == 1) ? 50 : 25);
            int   st = (l == 0) ? 0 : ((l == 1) ? 10000 : 12500);
            float x = fmaf(rx, fS, ox) - 0.5f;   // == (rx + ox/fS)*fS - 0.5
            float y = fmaf(ry, fS, oy) - 0.5f;
            float x0f = floorf(x), y0f = floorf(y);
            float fx = x - x0f, fy = y - y0f;
            int x0 = (int)x0f, y0 = (int)y0f;
            int x1 = x0 + 1,  y1 = y0 + 1;
            int cx0 = imin(imax(x0, 0), Wl - 1), cx1 = imin(imax(x1, 0), Wl - 1);
            int cy0 = imin(imax(y0, 0), Wl - 1), cy1 = imin(imax(y1, 0), Wl - 1);
            float vx0 = (x0 >= 0 && x0 < Wl) ? 1.0f : 0.0f;
            float vx1 = (x1 >= 0 && x1 < Wl) ? 1.0f : 0.0f;
            float vy0 = (y0 >= 0 && y0 < Wl) ? 1.0f : 0.0f;
            float vy1 = (y1 >= 0 && y1 < Wl) ? 1.0f : 0.0f;
            int s = wid * 104 + h * 13 + p;
            metaIdx[s] = make_int4((st + cy0 * Wl + cx0) << 9, (st + cy0 * Wl + cx1) << 9,
                                   (st + cy1 * Wl + cx0) << 9, (st + cy1 * Wl + cx1) << 9);
            metaW[s] = make_float4((1.0f - fx) * (1.0f - fy) * aw * vx0 * vy0,
                                   fx * (1.0f - fy) * aw * vx1 * vy0,
                                   (1.0f - fx) * fy * aw * vx0 * vy1,
                                   fx * fy * aw * vx1 * vy1);
        }
    }
    __syncthreads();

    int h  = lane >> 3;
    int bs = __builtin_amdgcn_readfirstlane(b);
    const char* vb = (const char*)(v + (size_t)bs * NVTOT * CDIM);
    int hoff = lane * 8;    // (h*32 + c8*4) * 2 bytes
    int sB   = wid * 104 + h * 13;
    float4 acc = {0.0f, 0.0f, 0.0f, 0.0f};

    // ---- pipeline prologue: stages A (p=0) and B (p=1) in flight ----
    int4   miA = metaIdx[sB + 0];
    float4 mwA = metaW[sB + 0];
    u64 a0 = *(const u64*)(vb + (unsigned)(miA.x + hoff));
    u64 a1 = *(const u64*)(vb + (unsigned)(miA.y + hoff));
    u64 a2 = *(const u64*)(vb + (unsigned)(miA.z + hoff));
    u64 a3 = *(const u64*)(vb + (unsigned)(miA.w + hoff));
    int4   miB = metaIdx[sB + 1];
    float4 mwB = metaW[sB + 1];
    u64 b0 = *(const u64*)(vb + (unsigned)(miB.x + hoff));
    u64 b1 = *(const u64*)(vb + (unsigned)(miB.y + hoff));
    u64 b2 = *(const u64*)(vb + (unsigned)(miB.z + hoff));
    u64 b3 = *(const u64*)(vb + (unsigned)(miB.w + hoff));

    #pragma unroll
    for (int p = 0; p < 12; p++) {
        // issue stage N (p+2); tail iterations re-load slot 11 (harmless, L1-hot)
        int pn = (p < 10) ? (p + 2) : 11;
        int4   miN = metaIdx[sB + pn];
        float4 mwN = metaW[sB + pn];
        u64 n0 = *(const u64*)(vb + (unsigned)(miN.x + hoff));
        u64 n1 = *(const u64*)(vb + (unsigned)(miN.y + hoff));
        u64 n2 = *(const u64*)(vb + (unsigned)(miN.z + hoff));
        u64 n3 = *(const u64*)(vb + (unsigned)(miN.w + hoff));

        // consume stage A (waits only on A's 4 loads; B/N stay in flight)
        {
            unsigned d0 = (unsigned)a0, d1 = (unsigned)(a0 >> 32);
            acc.x = fmaf(mwA.x, __uint_as_float(d0 << 16), acc.x);
            acc.y = fmaf(mwA.x, __uint_as_float(d0 & 0xffff0000u), acc.y);
            acc.z = fmaf(mwA.x, __uint_as_float(d1 << 16), acc.z);
            acc.w = fmaf(mwA.x, __uint_as_float(d1 & 0xffff0000u), acc.w);
        }
        {
            unsigned d0 = (unsigned)a1, d1 = (unsigned)(a1 >> 32);
            acc.x = fmaf(mwA.y, __uint_as_float(d0 << 16), acc.x);
            acc.y = fmaf(mwA.y, __uint_as_float(d0 & 0xffff0000u), acc.y);
            acc.z = fmaf(mwA.y, __uint_as_float(d1 << 16), acc.z);
            acc.w = fmaf(mwA.y, __uint_as_float(d1 & 0xffff0000u), acc.w);
        }
        {
            unsigned d0 = (unsigned)a2, d1 = (unsigned)(a2 >> 32);
            acc.x = fmaf(mwA.z, __uint_as_float(d0 << 16), acc.x);
            acc.y = fmaf(mwA.z, __uint_as_float(d0 & 0xffff0000u), acc.y);
            acc.z = fmaf(mwA.z, __uint_as_float(d1 << 16), acc.z);
            acc.w = fmaf(mwA.z, __uint_as_float(d1 & 0xffff0000u), acc.w);
        }
        {
            unsigned d0 = (unsigned)a3, d1 = (unsigned)(a3 >> 32);
            acc.x = fmaf(mwA.w, __uint_as_float(d0 << 16), acc.x);
            acc.y = fmaf(mwA.w, __uint_as_float(d0 & 0xffff0000u), acc.y);
            acc.z = fmaf(mwA.w, __uint_as_float(d1 << 16), acc.z);
            acc.w = fmaf(mwA.w, __uint_as_float(d1 & 0xffff0000u), acc.w);
        }

        // rotate: B -> A, N -> B
        a0 = b0; a1 = b1; a2 = b2; a3 = b3; mwA = mwB;
        b0 = n0; b1 = n1; b2 = n2; b3 = n3; mwB = mwN;
    }
    *(u64*)(out + (size_t)t * CDIM + lane * 4) = pack4(acc);
}

// ---------------------------------------------------------------- launch
extern "C" void kernel_launch(void* const* d_in, const int* in_sizes, int n_in,
                              void* d_out, int out_size, void* d_ws, size_t ws_size,
                              hipStream_t stream)
{
    const float* query = (const float*)d_in[0];
    const float* value = (const float*)d_in[1];
    const float* qpos  = (const float*)d_in[2];
    const float* ref   = (const float*)d_in[3];
    const float* ln1g  = (const float*)d_in[6];
    const float* ln1b  = (const float*)d_in[7];
    const float* ln2g  = (const float*)d_in[8];
    const float* ln2b  = (const float*)d_in[9];
    const float* Wv    = (const float*)d_in[10];
    const float* bv    = (const float*)d_in[11];
    const float* Woff  = (const float*)d_in[12];
    const float* boff  = (const float*)d_in[13];
    const float* Wat   = (const float*)d_in[14];
    const float* bat   = (const float*)d_in[15];
    const float* Wout  = (const float*)d_in[16];
    const float* bout  = (const float*)d_in[17];
    const float* W1    = (const float*)d_in[18];
    const float* b1    = (const float*)d_in[19];
    const float* W2    = (const float*)d_in[20];
    const float* b2    = (const float*)d_in[21];
    float* out = (float*)d_out;
    char*  ws  = (char*)d_ws;

    static bool attr_set = false;
    if (!attr_set) {
        hipFuncSetAttribute((const void*)ffn_k,
                            hipFuncAttributeMaxDynamicSharedMemorySize, 131072);
        attr_set = true;
    }

    const size_t MB = 1024 * 1024;
    __hip_bfloat16* Wvt   = (__hip_bfloat16*)(ws + 0);        // 256*256
    __hip_bfloat16* Wct   = (__hip_bfloat16*)(ws + 131072);   // 384*256 combined proj
    __hip_bfloat16* Woutt = (__hip_bfloat16*)(ws + 327680);   // 256*256
    __hip_bfloat16* W1t   = (__hip_bfloat16*)(ws + 458752);   // 1024*256 frag-packed
    __hip_bfloat16* W2t   = (__hip_bfloat16*)(ws + 983040);   // 256*1024 frag-packed
    float*          bcomb = (float*)(ws + 1507328);           // 288 floats
    __hip_bfloat16* qbf   = (__hip_bfloat16*)(ws + 2  * MB);  // 16.78 MB; reused as h
    __hip_bfloat16* aoutb = (__hip_bfloat16*)(ws + 19 * MB);  // 16.78 MB
    __hip_bfloat16* vbf   = (__hip_bfloat16*)(ws + 36 * MB);  // 13.44 MB bf16 value input
    __hip_bfloat16* vbuf  = (__hip_bfloat16*)(ws + 50 * MB);  // 13.44 MB projected v [row][h*d]
    __hip_bfloat16* xbf   = (__hip_bfloat16*)(ws + 64 * MB);  // 16.78 MB x (bf16)
    __hip_bfloat16* cbuf  = (__hip_bfloat16*)(ws + 81 * MB);  // 18.87 MB fused proj
    __hip_bfloat16* hbf   = qbf;

    // 1. prep: weights->bf16 (transposed / frag-packed), value->bf16, LN1(+pos)->qbf
    prep_k<<<WT_BLOCKS + CVT_BLOCKS + LN_BLOCKS, 256, 0, stream>>>(
        Wv, Woff, Wat, Wout, W1, W2, boff, bat, value, query, qpos, ln1g, ln1b,
        Wvt, Wct, Woutt, W1t, W2t, bcomb, vbf, qbf);
    // 2+3 merged: v-proj (z=0) and fused proj (z=1) in one launch
    mmj_k<<<dim3(256, 3, 2), 256, 0, stream>>>(
        vbf, Wvt, bv, vbuf, qbf, Wct, bcomb, cbuf);
    // 4. sampling (inline softmax) -> aout bf16
    sample_k<<<NTOK / 4, 256, 0, stream>>>(vbuf, cbuf, ref, aoutb);
    // 5. x = query + aout @ W_out + b_out -> xbf (bf16)
    mm_k<<<dim3(NTOK / 128, 2), 256, 0, stream>>>(
        aoutb, Woutt, bout, query, xbf, NTOK, 256, 256, EP_RES_F2BF);
    // 6. h = LN2(x) bf16
    ln2_k<<<NTOK / 4, 256, 0, stream>>>(xbf, ln2g, ln2b, hbf);
    // 7+8 fused: out = x + gelu(h@W1+b1)@W2 + b2  (fp32 to d_out)
    ffn_k<<<NTOK / 128, 512, 131072, stream>>>(hbf, W1t, b1, W2t, b2, xbf, out);
}

// Round 13
// 327.826 us; speedup vs baseline: 1.0333x; 1.0333x over previous
//
#include <hip/hip_runtime.h>
#include <hip/hip_bf16.h>

// Problem constants (fixed by setup_inputs)
#define BQ      2
#define QLEN    16384            // 128*128
#define CDIM    256
#define HEADS   8
#define LEV     3
#define PTS     4
#define DHEAD   32
#define NVTOT   13125            // 100*100 + 50*50 + 25*25
#define FDIM    1024
#define NTOK    (BQ*QLEN)        // 32768
#define MROWS_V (BQ*NVTOT)       // 26250
#define NPROJ   288              // 192 offsets + 96 attn logits, fused

typedef __attribute__((ext_vector_type(8))) short short8;     // 8 bf16 = 4 VGPRs
typedef __attribute__((ext_vector_type(4))) float floatx4;    // MFMA acc
typedef unsigned long long u64;

typedef const __attribute__((address_space(1))) unsigned int gu32;
typedef __attribute__((address_space(3))) unsigned int lu32;

__device__ __forceinline__ int imin(int a, int b){ return a<b?a:b; }
__device__ __forceinline__ int imax(int a, int b){ return a>b?a:b; }

__device__ __forceinline__ float bf2f(unsigned short u){ return __uint_as_float((unsigned)u << 16); }
__device__ __forceinline__ unsigned short f2bf(float f)
{
    __hip_bfloat16 h = __float2bfloat16(f);
    return *(unsigned short*)&h;
}
__device__ __forceinline__ u64 pack4(float4 v)
{
    return (u64)f2bf(v.x) | ((u64)f2bf(v.y) << 16)
         | ((u64)f2bf(v.z) << 32) | ((u64)f2bf(v.w) << 48);
}
__device__ __forceinline__ float4 unpack4(u64 c)
{
    float4 v;
    v.x = bf2f((unsigned short)(c));
    v.y = bf2f((unsigned short)(c >> 16));
    v.z = bf2f((unsigned short)(c >> 32));
    v.w = bf2f((unsigned short)(c >> 48));
    return v;
}

// tanh-gelu via exp + hardware rcp (no div sequence); err ~3e-4, saturation-safe
__device__ __forceinline__ float gelu_f(float x)
{
    float u2 = x * x;
    float a  = x * fmaf(0.0713548163f, u2, 1.5957691216f);  // 2u
    float e  = __expf(a);
    float r  = __builtin_amdgcn_rcpf(e + 1.0f);
    return fmaf(-x, r, x);   // x * e/(e+1)
}

// LayerNorm core: one wave per token (4 ch per lane), bf16 out
__device__ __forceinline__ void ln_core(float4 v, const float* __restrict__ pos, int tok,
                                        const float* __restrict__ g, const float* __restrict__ b,
                                        int lane, __hip_bfloat16* __restrict__ out)
{
    float s = v.x + v.y + v.z + v.w;
    #pragma unroll
    for (int o = 32; o > 0; o >>= 1) s += __shfl_down(s, o);
    s = __shfl(s, 0);
    float mean = s * (1.0f / 256.0f);
    float4 c; c.x = v.x - mean; c.y = v.y - mean; c.z = v.z - mean; c.w = v.w - mean;
    float q2 = c.x*c.x + c.y*c.y + c.z*c.z + c.w*c.w;
    #pragma unroll
    for (int o = 32; o > 0; o >>= 1) q2 += __shfl_down(q2, o);
    q2 = __shfl(q2, 0);
    float rstd = rsqrtf(q2 * (1.0f / 256.0f) + 1e-5f);
    float4 gg = ((const float4*)g)[lane];
    float4 bb = ((const float4*)b)[lane];
    float4 o4;
    o4.x = c.x * rstd * gg.x + bb.x;
    o4.y = c.y * rstd * gg.y + bb.y;
    o4.z = c.z * rstd * gg.z + bb.z;
    o4.w = c.w * rstd * gg.w + bb.w;
    if (pos) {
        float4 p = ((const float4*)(pos + (size_t)tok * CDIM))[lane];
        o4.x += p.x; o4.y += p.y; o4.z += p.z; o4.w += p.w;
    }
    *(u64*)(out + (size_t)tok * CDIM + lane * 4) = pack4(o4);
}

// ---------------------------------------------------------------- prep: weight transpose+cvt + value cvt + LN1, one launch
// W1/W2 are written in MFMA-fragment order for ffn_k: chunk index
// fc*4096 + wn*1024 + r*64 + lane (16B per lane) so every ffn_k weight load
// is a fully coalesced 64-lane x 16B request.
#define WT_BLOCKS  2946
#define CVT_BLOCKS 6563          // ceil(26250*256/4 / 256)
#define LN_BLOCKS  8192          // NTOK/4

__global__ __launch_bounds__(256)
void prep_k(const float* __restrict__ Wv,  const float* __restrict__ Woff,
            const float* __restrict__ Wat, const float* __restrict__ Wout,
            const float* __restrict__ W1,  const float* __restrict__ W2,
            const float* __restrict__ boff, const float* __restrict__ bat,
            const float* __restrict__ value, const float* __restrict__ query,
            const float* __restrict__ qpos,  const float* __restrict__ ln1g,
            const float* __restrict__ ln1b,
            __hip_bfloat16* __restrict__ o_v,  __hip_bfloat16* __restrict__ o_c,
            __hip_bfloat16* __restrict__ o_out,
            __hip_bfloat16* __restrict__ o_1,  __hip_bfloat16* __restrict__ o_2,
            float* __restrict__ o_bc,
            __hip_bfloat16* __restrict__ vbf,  __hip_bfloat16* __restrict__ qbf)
{
    int bx = blockIdx.x;
    if (bx < WT_BLOCKS) {
        int gid = bx * 256 + threadIdx.x;
        if (gid < 65536) {                      // Wv  -> [256][256]
            int idx = gid, n = idx >> 8, k = idx & 255;
            o_v[idx] = __float2bfloat16(Wv[(size_t)k * 256 + n]);
        } else if (gid < 163840) {              // combined proj -> [384][256]
            int idx = gid - 65536, n = idx >> 8, k = idx & 255;
            float v = 0.0f;
            if (n < 192)       v = Woff[(size_t)k * 192 + n];
            else if (n < 288)  v = Wat[(size_t)k * 96 + (n - 192)];
            o_c[idx] = __float2bfloat16(v);
        } else if (gid < 229376) {              // Wout -> [256][256]
            int idx = gid - 163840, n = idx >> 8, k = idx & 255;
            o_out[idx] = __float2bfloat16(Wout[(size_t)k * 256 + n]);
        } else if (gid < 491520) {              // W1 -> ffn frag-packed [32768 chunks][8]
            int idx  = gid - 229376;
            int e    = idx & 7;
            int c    = idx >> 3;
            int lane = c & 63, lm = lane & 15, lk = lane >> 4;
            int r    = (c >> 6) & 15;
            int wn   = (c >> 10) & 3;
            int fc   = c >> 12;
            int i    = r & 1, ks = (r >> 1) & 1, kt = r >> 2;
            int row  = fc * 128 + wn * 32 + i * 16 + lm;   // F index 0..1023
            int col  = kt * 64 + ks * 32 + lk * 8 + e;     // K index 0..255
            o_1[idx] = __float2bfloat16(W1[(size_t)col * 1024 + row]);
        } else if (gid < 753664) {              // W2 -> ffn frag-packed [32768 chunks][8]
            int idx  = gid - 491520;
            int e    = idx & 7;
            int c    = idx >> 3;
            int lane = c & 63, lm = lane & 15, lk = lane >> 4;
            int r    = (c >> 6) & 15;
            int wn   = (c >> 10) & 3;
            int fc   = c >> 12;
            int i2   = r & 3, ks2 = r >> 2;
            int row  = wn * 64 + i2 * 16 + lm;             // C index 0..255
            int col  = fc * 128 + ks2 * 32 + lk * 8 + e;   // F index 0..1023
            o_2[idx] = __float2bfloat16(W2[(size_t)col * 256 + row]);
        } else if (gid < 753952) {              // combined bias [288]
            int idx = gid - 753664;
            o_bc[idx] = (idx < 192) ? boff[idx] : bat[idx - 192];
        }
    } else if (bx < WT_BLOCKS + CVT_BLOCKS) {
        int i = (bx - WT_BLOCKS) * 256 + threadIdx.x;
        if (i < MROWS_V * CDIM / 4) {
            float4 v = ((const float4*)value)[i];
            *(u64*)(vbf + (size_t)i * 4) = pack4(v);
        }
    } else {
        int tok  = (bx - WT_BLOCKS - CVT_BLOCKS) * 4 + (threadIdx.x >> 6);
        int lane = threadIdx.x & 63;
        float4 v = ((const float4*)(query + (size_t)tok * CDIM))[lane];
        ln_core(v, qpos, tok, ln1g, ln1b, lane, qbf);
    }
}

// ---------------------------------------------------------------- LN2: bf16 in, bf16 out
__global__ __launch_bounds__(256)
void ln2_k(const __hip_bfloat16* __restrict__ x, const float* __restrict__ g,
           const float* __restrict__ b, __hip_bfloat16* __restrict__ out)
{
    int tok  = blockIdx.x * 4 + (threadIdx.x >> 6);
    int lane = threadIdx.x & 63;
    float4 v = unpack4(((const u64*)(x + (size_t)tok * CDIM))[lane]);
    ln_core(v, nullptr, tok, g, b, lane, out);
}

// ---------------------------------------------------------------- bf16 MFMA GEMM (transposed-acc + single-pass bf16-staged epilogue)
// modes: 0 = plain bf16 out; 1 = gelu bf16 out; 2 = +fp32 res -> bf16 out; 3 = +bf16 res -> fp32 out
enum { EP_PLAIN_BF16 = 0, EP_GELU_BF16 = 1, EP_RES_F2BF = 2, EP_RES_BF2F = 3 };

__global__ __launch_bounds__(256)
void mm_k(const __hip_bfloat16* __restrict__ A, const __hip_bfloat16* __restrict__ Bt,
          const float* __restrict__ bias, const void* __restrict__ res,
          void* __restrict__ Cout, int M, int N, int K, int mode)
{
    __shared__ float4 smem4[2048];                    // 32 KB: tiles, then bf16 staging
    __hip_bfloat16* Ws = (__hip_bfloat16*)smem4;          // 16 KB weight tile
    __hip_bfloat16* Ts = (__hip_bfloat16*)smem4 + 128*64; // 16 KB token tile
    u64* st = (u64*)smem4;                                // staging: 128 tok x 32 chunks x 8B
    int t = threadIdx.x;
    int lane = t & 63;
    int wave = t >> 6;
    int wm = wave >> 1, wn = wave & 1;
    int lm = lane & 15, lk = lane >> 4;
    int m0 = blockIdx.x * 128;     // token base
    int n0 = blockIdx.y * 128;     // channel base

    floatx4 acc[4][4];             // [i: channel subtile][j: token subtile]
    #pragma unroll
    for (int i = 0; i < 4; i++)
        #pragma unroll
        for (int j = 0; j < 4; j++) acc[i][j] = (floatx4)0.0f;

    for (int kt = 0; kt < K; kt += 64) {
        #pragma unroll
        for (int i = 0; i < 4; i++) {
            int cc  = i * 256 + t;          // LDS chunk 0..1023 (16 B each)
            int row = cc >> 3;              // 0..127
            int c   = cc & 7;
            int kc  = c ^ (row & 7);        // XOR swizzle
            int ra  = m0 + row; if (ra >= M) ra = M - 1;   // token row clamp
            const __hip_bfloat16* gw = Bt + (size_t)(n0 + row) * K + kt + kc * 8;
            const __hip_bfloat16* gt = A  + (size_t)ra * K + kt + kc * 8;
            __builtin_amdgcn_global_load_lds((gu32*)gw, (lu32*)(Ws + cc * 8), 16, 0, 0);
            __builtin_amdgcn_global_load_lds((gu32*)gt, (lu32*)(Ts + cc * 8), 16, 0, 0);
        }
        __syncthreads();
        #pragma unroll
        for (int ks = 0; ks < 2; ks++) {
            short8 wf[4], tf[4];
            #pragma unroll
            for (int i = 0; i < 4; i++) {
                int rw = wn * 64 + i * 16 + lm;            // channel row
                int cw = (ks * 4 + lk) ^ (rw & 7);
                wf[i] = *(const short8*)(Ws + (rw * 8 + cw) * 8);
                int rt = wm * 64 + i * 16 + lm;            // token row
                int ct = (ks * 4 + lk) ^ (rt & 7);
                tf[i] = *(const short8*)(Ts + (rt * 8 + ct) * 8);
            }
            #pragma unroll
            for (int i = 0; i < 4; i++)
                #pragma unroll
                for (int j = 0; j < 4; j++)
                    acc[i][j] = __builtin_amdgcn_mfma_f32_16x16x32_bf16(wf[i], tf[j], acc[i][j], 0, 0, 0);
        }
        __syncthreads();
    }

    // ---- write side: all waves stage bias-added bf16 frags ----
    #pragma unroll
    for (int i = 0; i < 4; i++) {
        int chan = n0 + wn * 64 + i * 16 + lk * 4;
        float4 b4 = make_float4(0.f, 0.f, 0.f, 0.f);
        if (chan < N) b4 = *(const float4*)(bias + chan);
        int c4 = wn * 16 + i * 4 + lk;          // chan chunk 0..31
        #pragma unroll
        for (int j = 0; j < 4; j++) {
            int tl = wm * 64 + j * 16 + lm;     // token-local 0..127
            float4 v;
            v.x = acc[i][j][0] + b4.x;
            v.y = acc[i][j][1] + b4.y;
            v.z = acc[i][j][2] + b4.z;
            v.w = acc[i][j][3] + b4.w;
            st[tl * 32 + (c4 ^ (tl & 31))] = pack4(v);
        }
    }
    __syncthreads();

    // ---- read side: coalesced row-contiguous stores ----
    int rel = (t & 31) * 4;
    int c4r = t & 31;
    #pragma unroll
    for (int it = 0; it < 16; it++) {
        int tl   = it * 8 + (t >> 5);
        int tok  = m0 + tl;
        int chan = n0 + rel;
        if (tok >= M || chan >= N) continue;
        u64 chunk = st[tl * 32 + (c4r ^ (tl & 31))];
        if (mode == EP_PLAIN_BF16) {
            *(u64*)((__hip_bfloat16*)Cout + (size_t)tok * N + chan) = chunk;
        } else if (mode == EP_GELU_BF16) {
            float4 v = unpack4(chunk);
            v.x = gelu_f(v.x); v.y = gelu_f(v.y); v.z = gelu_f(v.z); v.w = gelu_f(v.w);
            *(u64*)((__hip_bfloat16*)Cout + (size_t)tok * N + chan) = pack4(v);
        } else if (mode == EP_RES_F2BF) {
            float4 v = unpack4(chunk);
            float4 rr = *(const float4*)((const float*)res + (size_t)tok * N + chan);
            v.x += rr.x; v.y += rr.y; v.z += rr.z; v.w += rr.w;
            *(u64*)((__hip_bfloat16*)Cout + (size_t)tok * N + chan) = pack4(v);
        } else { // EP_RES_BF2F
            float4 v = unpack4(chunk);
            float4 rr = unpack4(*(const u64*)((const __hip_bfloat16*)res + (size_t)tok * N + chan));
            v.x += rr.x; v.y += rr.y; v.z += rr.z; v.w += rr.w;
            *(float4*)((float*)Cout + (size_t)tok * N + chan) = v;
        }
    }
}

// ---------------------------------------------------------------- fused FFN: out = x + gelu(h@W1+b1)@W2 + b2
// Round-8 configuration, measured 61.0us three times (best known):
// 128-token tile, 512 threads, 2-barrier/fc, frag-packed coalesced weight
// loads, in-place w1c prefetch. Backend gives 512-thread blocks 128 VGPRs
// (observed rounds 4-8 regardless of launch_bounds hint); mild ~5MB spill.
// ROUND-12 A/B closed: mmj z-grid merge of the two proj GEMMs cost +9.5us
// (338.7 vs 329.2 with this identical ffn_k) -> separate mm_k launches kept.
// LN2-in-LDS fusion also measured regression (round 11: ffn 61->67.2us).
__global__ __launch_bounds__(512, 1)
void ffn_k(const __hip_bfloat16* __restrict__ h,    // [NTOK][256] bf16 (LN2 out)
           const __hip_bfloat16* __restrict__ W1p,  // frag-packed [32768][8] bf16
           const float* __restrict__ b1,            // [1024]
           const __hip_bfloat16* __restrict__ W2p,  // frag-packed [32768][8] bf16
           const float* __restrict__ b2,            // [256]
           const __hip_bfloat16* __restrict__ xres, // [NTOK][256] bf16 residual
           float* __restrict__ out)                 // [NTOK][256] fp32
{
    extern __shared__ char smem_dyn[];
    __hip_bfloat16* As = (__hip_bfloat16*)smem_dyn;           // 64KB: 4 kt-subtiles, mm_k layout

    int t    = threadIdx.x;
    int lane = t & 63;
    int wave = t >> 6;          // 0..7
    int wm   = wave >> 2;       // token half (64)
    int wn   = wave & 3;        // F quarter (32) in GEMM1 / C quarter (64) in GEMM2
    int lm   = lane & 15, lk = lane >> 4;
    int m0   = blockIdx.x * 128;

    const short8* W1v = (const short8*)W1p;
    const short8* W2v = (const short8*)W2p;
    int wb = wn * 1024 + lane;          // per-wave chunk base (lane-resolved)

    // ---- stage h-tile once: [4 kt][128 row][8 chunks of 16B], XOR swizzled ----
    #pragma unroll
    for (int i = 0; i < 8; i++) {
        int cc  = i * 512 + t;          // 0..4095 chunks
        int kt  = cc >> 10;
        int rem = cc & 1023;
        int row = rem >> 3;
        int c   = rem & 7;
        int kc  = c ^ (row & 7);
        const __hip_bfloat16* src = h + (size_t)(m0 + row) * 256 + kt * 64 + kc * 8;
        __builtin_amdgcn_global_load_lds((gu32*)src, (lu32*)(As + cc * 8), 16, 0, 0);
    }

    floatx4 acc2[4][4];                 // [i2: C subtile][j: tok subtile]
    #pragma unroll
    for (int i = 0; i < 4; i++)
        #pragma unroll
        for (int j = 0; j < 4; j++) acc2[i][j] = (floatx4)0.0f;

    // ---- preload W1 frags for fc=0 (coalesced; overlaps the staging drain) ----
    short8 w1c[16];                     // [kt*4 + ks*2 + i]
    #pragma unroll
    for (int r = 0; r < 16; r++) w1c[r] = W1v[wb + r * 64];

    __syncthreads();                    // As ready (vmcnt drained by barrier)

    #pragma unroll 1
    for (int fc = 0; fc < 8; fc++) {
        int f0 = fc * 128;
        __hip_bfloat16* gs = (__hip_bfloat16*)(smem_dyn + 65536 + (fc & 1) * 32768);

        // ---- GEMM1: acc1[f][tok] over K=256, W1 frags already in registers ----
        floatx4 acc1[2][4];
        #pragma unroll
        for (int i = 0; i < 2; i++)
            #pragma unroll
            for (int j = 0; j < 4; j++) acc1[i][j] = (floatx4)0.0f;

        #pragma unroll
        for (int kt = 0; kt < 4; kt++) {
            #pragma unroll
            for (int ks = 0; ks < 2; ks++) {
                short8 tf[4];
                #pragma unroll
                for (int j = 0; j < 4; j++) {
                    int rt = wm * 64 + j * 16 + lm;
                    int ct = (ks * 4 + lk) ^ (rt & 7);
                    tf[j] = *(const short8*)(As + (kt * 1024 + rt * 8 + ct) * 8);
                }
                #pragma unroll
                for (int i = 0; i < 2; i++)
                    #pragma unroll
                    for (int j = 0; j < 4; j++)
                        acc1[i][j] = __builtin_amdgcn_mfma_f32_16x16x32_bf16(
                            w1c[kt * 4 + ks * 2 + i], tf[j], acc1[i][j], 0, 0, 0);
            }
        }

        // ---- epilogue1: bias + gelu -> bf16 -> gs (XOR-swizzled [tok][16 chunks]) ----
        #pragma unroll
        for (int i = 0; i < 2; i++) {
            float4 bb = *(const float4*)(b1 + f0 + wn * 32 + i * 16 + lk * 4);
            int c = wn * 4 + i * 2 + (lk >> 1);      // 16B chunk index 0..15
            #pragma unroll
            for (int j = 0; j < 4; j++) {
                int tok = wm * 64 + j * 16 + lm;
                float4 v;
                v.x = gelu_f(acc1[i][j][0] + bb.x);
                v.y = gelu_f(acc1[i][j][1] + bb.y);
                v.z = gelu_f(acc1[i][j][2] + bb.z);
                v.w = gelu_f(acc1[i][j][3] + bb.w);
                int sc = c ^ (tok & 7);
                *(u64*)((char*)gs + tok * 256 + sc * 16 + (lk & 1) * 8) = pack4(v);
            }
        }

        // ---- W2 frags + next-fc W1 (in place into w1c; dead after GEMM1),
        //      both issued before the barrier so latency hides under it ----
        short8 w2f[16];                 // [ks2*4 + i2]
        #pragma unroll
        for (int r = 0; r < 16; r++) w2f[r] = W2v[fc * 4096 + wb + r * 64];

        int fcn = (fc < 7) ? fc + 1 : 7;
        #pragma unroll
        for (int r = 0; r < 16; r++) w1c[r] = W1v[fcn * 4096 + wb + r * 64];

        __syncthreads();                // gs writes visible to all waves

        // ---- GEMM2: acc2 += W2 x g over K=128 ----
        #pragma unroll
        for (int ks2 = 0; ks2 < 4; ks2++) {
            short8 tf2[4];
            #pragma unroll
            for (int j = 0; j < 4; j++) {
                int tok = wm * 64 + j * 16 + lm;
                int sc = (ks2 * 4 + lk) ^ (tok & 7);
                tf2[j] = *(const short8*)((char*)gs + tok * 256 + sc * 16);
            }
            #pragma unroll
            for (int i2 = 0; i2 < 4; i2++)
                #pragma unroll
                for (int j = 0; j < 4; j++)
                    acc2[i2][j] = __builtin_amdgcn_mfma_f32_16x16x32_bf16(
                        w2f[ks2 * 4 + i2], tf2[j], acc2[i2][j], 0, 0, 0);
        }
        // no trailing barrier: next fc writes the other gs buffer; the barrier
        // above (fc+1) orders GEMM2(fc) reads before epilogue1(fc+2) reuse.
    }

    // ---- final epilogue: + b2 + residual(bf16) -> fp32 out, 64B/tok segments ----
    #pragma unroll
    for (int i2 = 0; i2 < 4; i2++) {
        int c0 = wn * 64 + i2 * 16 + lk * 4;
        float4 bb = *(const float4*)(b2 + c0);
        #pragma unroll
        for (int j = 0; j < 4; j++) {
            int tok = m0 + wm * 64 + j * 16 + lm;
            float4 r = unpack4(*(const u64*)(xres + (size_t)tok * 256 + c0));
            float4 v;
            v.x = acc2[i2][j][0] + bb.x + r.x;
            v.y = acc2[i2][j][1] + bb.y + r.y;
            v.z = acc2[i2][j][2] + bb.z + r.z;
            v.w = acc2[i2][j][3] + bb.w + r.w;
            *(float4*)(out + (size_t)tok * 256 + c0) = v;
        }
    }
}

// ---------------------------------------------------------------- deformable sampling
// vbuf layout [b*NVTOT+pix][h*d]: wave-uniform base + 32-bit byte offsets (meta
// stores pix<<9); lane = (h, c8), per-lane byte bias = lane*8.
// Gather loop is depth-2 software-pipelined: point p+2's 4 gathers are issued
// while point p is consumed, so the compiler emits counted vmcnt (8 loads in
// flight) instead of draining vmcnt(0) every point. launch_bounds(256,6) caps
// VGPRs at ~85 so the unroll can't hoist all 48 loads and kill occupancy.
__global__ __launch_bounds__(256, 6)
void sample_k(const __hip_bfloat16* __restrict__ v, const __hip_bfloat16* __restrict__ cbuf,
              const float* __restrict__ ref, __hip_bfloat16* __restrict__ out)
{
    __shared__ int4   metaIdx[4 * 104];   // stride 13 slots -> conflict-free
    __shared__ float4 metaW[4 * 104];

    int wid  = threadIdx.x >> 6;
    int lane = threadIdx.x & 63;
    int t    = blockIdx.x * 4 + wid;
    int b    = t >> 14;
    float rx = ref[(size_t)t * 2 + 0];
    float ry = ref[(size_t)t * 2 + 1];
    const __hip_bfloat16* crow = cbuf + (size_t)t * NPROJ;

    #pragma unroll
    for (int rnd = 0; rnd < 2; rnd++) {
        int slot = rnd * 64 + lane;
        int h = slot >> 4, p = slot & 15;
        int pc = imin(p, 11);
        unsigned upk = *(const unsigned*)(crow + h * 24 + pc * 2);
        float ox = bf2f((unsigned short)upk);
        float oy = bf2f((unsigned short)(upk >> 16));
        float logit = bf2f(*(const unsigned short*)(crow + 192 + h * 12 + pc));
        float mx = logit;
        #pragma unroll
        for (int o = 8; o > 0; o >>= 1) mx = fmaxf(mx, __shfl_xor(mx, o, 16));
        float e = (p < 12) ? __expf(logit - mx) : 0.0f;
        float ssum = e;
        #pragma unroll
        for (int o = 8; o > 0; o >>= 1) ssum += __shfl_xor(ssum, o, 16);
        float aw = e * __builtin_amdgcn_rcpf(ssum);

        if (p < 12) {
            int l = p >> 2;
            float fS = (l == 0) ? 100.0f : ((l == 1) ? 50.0f : 25.0f);
            int   Wl = (l == 0) ? 100 : ((l == 1) ? 50 : 25);
            int   st = (l == 0) ? 0 : ((l == 1) ? 10000 : 12500);
            float x = fmaf(rx, fS, ox) - 0.5f;   // == (rx + ox/fS)*fS - 0.5
            float y = fmaf(ry, fS, oy) - 0.5f;
            float x0f = floorf(x), y0f = floorf(y);
            float fx = x - x0f, fy = y - y0f;
            int x0 = (int)x0f, y0 = (int)y0f;
            int x1 = x0 + 1,  y1 = y0 + 1;
            int cx0 = imin(imax(x0, 0), Wl - 1), cx1 = imin(imax(x1, 0), Wl - 1);
            int cy0 = imin(imax(y0, 0), Wl - 1), cy1 = imin(imax(y1, 0), Wl - 1);
            float vx0 = (x0 >= 0 && x0 < Wl) ? 1.0f : 0.0f;
            float vx1 = (x1 >= 0 && x1 < Wl) ? 1.0f : 0.0f;
            float vy0 = (y0 >= 0 && y0 < Wl) ? 1.0f : 0.0f;
            float vy1 = (y1 >= 0 && y1 < Wl) ? 1.0f : 0.0f;
            int s = wid * 104 + h * 13 + p;
            metaIdx[s] = make_int4((st + cy0 * Wl + cx0) << 9, (st + cy0 * Wl + cx1) << 9,
                                   (st + cy1 * Wl + cx0) << 9, (st + cy1 * Wl + cx1) << 9);
            metaW[s] = make_float4((1.0f - fx) * (1.0f - fy) * aw * vx0 * vy0,
                                   fx * (1.0f - fy) * aw * vx1 * vy0,
                                   (1.0f - fx) * fy * aw * vx0 * vy1,
                                   fx * fy * aw * vx1 * vy1);
        }
    }
    __syncthreads();

    int h  = lane >> 3;
    int bs = __builtin_amdgcn_readfirstlane(b);
    const char* vb = (const char*)(v + (size_t)bs * NVTOT * CDIM);
    int hoff = lane * 8;    // (h*32 + c8*4) * 2 bytes
    int sB   = wid * 104 + h * 13;
    float4 acc = {0.0f, 0.0f, 0.0f, 0.0f};

    // ---- pipeline prologue: stages A (p=0) and B (p=1) in flight ----
    int4   miA = metaIdx[sB + 0];
    float4 mwA = metaW[sB + 0];
    u64 a0 = *(const u64*)(vb + (unsigned)(miA.x + hoff));
    u64 a1 = *(const u64*)(vb + (unsigned)(miA.y + hoff));
    u64 a2 = *(const u64*)(vb + (unsigned)(miA.z + hoff));
    u64 a3 = *(const u64*)(vb + (unsigned)(miA.w + hoff));
    int4   miB = metaIdx[sB + 1];
    float4 mwB = metaW[sB + 1];
    u64 b0 = *(const u64*)(vb + (unsigned)(miB.x + hoff));
    u64 b1 = *(const u64*)(vb + (unsigned)(miB.y + hoff));
    u64 b2 = *(const u64*)(vb + (unsigned)(miB.z + hoff));
    u64 b3 = *(const u64*)(vb + (unsigned)(miB.w + hoff));

    #pragma unroll
    for (int p = 0; p < 12; p++) {
        // issue stage N (p+2); tail iterations re-load slot 11 (harmless, L1-hot)
        int pn = (p < 10) ? (p + 2) : 11;
        int4   miN = metaIdx[sB + pn];
        float4 mwN = metaW[sB + pn];
        u64 n0 = *(const u64*)(vb + (unsigned)(miN.x + hoff));
        u64 n1 = *(const u64*)(vb + (unsigned)(miN.y + hoff));
        u64 n2 = *(const u64*)(vb + (unsigned)(miN.z + hoff));
        u64 n3 = *(const u64*)(vb + (unsigned)(miN.w + hoff));

        // consume stage A (waits only on A's 4 loads; B/N stay in flight)
        {
            unsigned d0 = (unsigned)a0, d1 = (unsigned)(a0 >> 32);
            acc.x = fmaf(mwA.x, __uint_as_float(d0 << 16), acc.x);
            acc.y = fmaf(mwA.x, __uint_as_float(d0 & 0xffff0000u), acc.y);
            acc.z = fmaf(mwA.x, __uint_as_float(d1 << 16), acc.z);
            acc.w = fmaf(mwA.x, __uint_as_float(d1 & 0xffff0000u), acc.w);
        }
        {
            unsigned d0 = (unsigned)a1, d1 = (unsigned)(a1 >> 32);
            acc.x = fmaf(mwA.y, __uint_as_float(d0 << 16), acc.x);
            acc.y = fmaf(mwA.y, __uint_as_float(d0 & 0xffff0000u), acc.y);
            acc.z = fmaf(mwA.y, __uint_as_float(d1 << 16), acc.z);
            acc.w = fmaf(mwA.y, __uint_as_float(d1 & 0xffff0000u), acc.w);
        }
        {
            unsigned d0 = (unsigned)a2, d1 = (unsigned)(a2 >> 32);
            acc.x = fmaf(mwA.z, __uint_as_float(d0 << 16), acc.x);
            acc.y = fmaf(mwA.z, __uint_as_float(d0 & 0xffff0000u), acc.y);
            acc.z = fmaf(mwA.z, __uint_as_float(d1 << 16), acc.z);
            acc.w = fmaf(mwA.z, __uint_as_float(d1 & 0xffff0000u), acc.w);
        }
        {
            unsigned d0 = (unsigned)a3, d1 = (unsigned)(a3 >> 32);
            acc.x = fmaf(mwA.w, __uint_as_float(d0 << 16), acc.x);
            acc.y = fmaf(mwA.w, __uint_as_float(d0 & 0xffff0000u), acc.y);
            acc.z = fmaf(mwA.w, __uint_as_float(d1 << 16), acc.z);
            acc.w = fmaf(mwA.w, __uint_as_float(d1 & 0xffff0000u), acc.w);
        }

        // rotate: B -> A, N -> B
        a0 = b0; a1 = b1; a2 = b2; a3 = b3; mwA = mwB;
        b0 = n0; b1 = n1; b2 = n2; b3 = n3; mwB = mwN;
    }
    *(u64*)(out + (size_t)t * CDIM + lane * 4) = pack4(acc);
}

// ---------------------------------------------------------------- launch
extern "C" void kernel_launch(void* const* d_in, const int* in_sizes, int n_in,
                              void* d_out, int out_size, void* d_ws, size_t ws_size,
                              hipStream_t stream)
{
    const float* query = (const float*)d_in[0];
    const float* value = (const float*)d_in[1];
    const float* qpos  = (const float*)d_in[2];
    const float* ref   = (const float*)d_in[3];
    const float* ln1g  = (const float*)d_in[6];
    const float* ln1b  = (const float*)d_in[7];
    const float* ln2g  = (const float*)d_in[8];
    const float* ln2b  = (const float*)d_in[9];
    const float* Wv    = (const float*)d_in[10];
    const float* bv    = (const float*)d_in[11];
    const float* Woff  = (const float*)d_in[12];
    const float* boff  = (const float*)d_in[13];
    const float* Wat   = (const float*)d_in[14];
    const float* bat   = (const float*)d_in[15];
    const float* Wout  = (const float*)d_in[16];
    const float* bout  = (const float*)d_in[17];
    const float* W1    = (const float*)d_in[18];
    const float* b1    = (const float*)d_in[19];
    const float* W2    = (const float*)d_in[20];
    const float* b2    = (const float*)d_in[21];
    float* out = (float*)d_out;
    char*  ws  = (char*)d_ws;

    static bool attr_set = false;
    if (!attr_set) {
        hipFuncSetAttribute((const void*)ffn_k,
                            hipFuncAttributeMaxDynamicSharedMemorySize, 131072);
        attr_set = true;
    }

    const size_t MB = 1024 * 1024;
    __hip_bfloat16* Wvt   = (__hip_bfloat16*)(ws + 0);        // 256*256
    __hip_bfloat16* Wct   = (__hip_bfloat16*)(ws + 131072);   // 384*256 combined proj
    __hip_bfloat16* Woutt = (__hip_bfloat16*)(ws + 327680);   // 256*256
    __hip_bfloat16* W1t   = (__hip_bfloat16*)(ws + 458752);   // 1024*256 frag-packed
    __hip_bfloat16* W2t   = (__hip_bfloat16*)(ws + 983040);   // 256*1024 frag-packed
    float*          bcomb = (float*)(ws + 1507328);           // 288 floats
    __hip_bfloat16* qbf   = (__hip_bfloat16*)(ws + 2  * MB);  // 16.78 MB; reused as h
    __hip_bfloat16* aoutb = (__hip_bfloat16*)(ws + 19 * MB);  // 16.78 MB
    __hip_bfloat16* vbf   = (__hip_bfloat16*)(ws + 36 * MB);  // 13.44 MB bf16 value input
    __hip_bfloat16* vbuf  = (__hip_bfloat16*)(ws + 50 * MB);  // 13.44 MB projected v [row][h*d]
    __hip_bfloat16* xbf   = (__hip_bfloat16*)(ws + 64 * MB);  // 16.78 MB x (bf16)
    __hip_bfloat16* cbuf  = (__hip_bfloat16*)(ws + 81 * MB);  // 18.87 MB fused proj
    __hip_bfloat16* hbf   = qbf;

    // 1. prep: weights->bf16 (transposed / frag-packed), value->bf16, LN1(+pos)->qbf
    prep_k<<<WT_BLOCKS + CVT_BLOCKS + LN_BLOCKS, 256, 0, stream>>>(
        Wv, Woff, Wat, Wout, W1, W2, boff, bat, value, query, qpos, ln1g, ln1b,
        Wvt, Wct, Woutt, W1t, W2t, bcomb, vbf, qbf);
    // 2. v-proj: vbuf[row][h*d] = value @ W_value + b_value  (plain coalesced bf16)
    mm_k<<<dim3((MROWS_V + 127) / 128, 2), 256, 0, stream>>>(
        vbf, Wvt, bv, nullptr, vbuf, MROWS_V, 256, 256, EP_PLAIN_BF16);
    // 3. fused proj: [offsets | attn logits] (bf16)
    mm_k<<<dim3(NTOK / 128, 3), 256, 0, stream>>>(
        qbf, Wct, bcomb, nullptr, cbuf, NTOK, NPROJ, 256, EP_PLAIN_BF16);
    // 4. sampling (inline softmax) -> aout bf16
    sample_k<<<NTOK / 4, 256, 0, stream>>>(vbuf, cbuf, ref, aoutb);
    // 5. x = query + aout @ W_out + b_out -> xbf (bf16)
    mm_k<<<dim3(NTOK / 128, 2), 256, 0, stream>>>(
        aoutb, Woutt, bout, query, xbf, NTOK, 256, 256, EP_RES_F2BF);
    // 6. h = LN2(x) bf16
    ln2_k<<<NTOK / 4, 256, 0, stream>>>(xbf, ln2g, ln2b, hbf);
    // 7+8 fused: out = x + gelu(h@W1+b1)@W2 + b2  (fp32 to d_out)
    ffn_k<<<NTOK / 128, 512, 131072, stream>>>(hbf, W1t, b1, W2t, b2, xbf, out);
}